// Round 9
// baseline (169.966 us; speedup 1.0000x reference)
//
#include <hip/hip_runtime.h>
#include <hip/hip_bf16.h>

// ClauseExtractor: B=8,S=512,D=256,MAX_SPAN=100,NUM_TYPES=15, N spans=46250.
// h_pre[b,(s,e)] = P[b,s] + Q[b,e],  P=E@Wenc[:256]+b_enc, Q=E@Wenc[256:]
// k2 rev8: PQ + width in f32 (rev7 profile: VALU 52% is the dominant pipe;
// 3 bf16->f32 unpack shifts per element were ~half of stage-1 VALU).
// Gathers read f32 (2x L2 traffic, 17 of 34.5 TB/s — headroom), convert to
// bf16 once after the math. Width table read directly from input wtab (WTB
// pack deleted). k1: no LDS epilogue, direct f32 stores. k-major LDS layout,
// one batch/block, no cross-MFMA hoists (rev6 spill lesson) — unchanged.

#define B_ 8
#define S_ 512
#define D_ 256
#define NSPANS 46250
#define NTILES 723  // ceil(46250/64)

typedef __bf16 bf16x8 __attribute__((ext_vector_type(8)));
typedef __bf16 bf16x4 __attribute__((ext_vector_type(4)));
typedef float float4_ __attribute__((ext_vector_type(4)));

#define MFMA16(a, b, c) __builtin_amdgcn_mfma_f32_16x16x32_bf16((a), (b), (c), 0, 0, 0)

// ---- workspace layout (bytes) ----
#define WS_STARTS 0u
#define WS_ENDS 185344u
#define WS_WENCP 370688u   // bf16[32][512][8]  = 262144
#define WS_WT 632832u      // bf16[32][256][8]  = 131072
#define WS_GT 763904u      // bf16[32][16][8]   = 8192
#define WS_BSC 772096u     // f32[256]
#define WS_GB 773120u      // f32[16]
#define WS_PQ 786432u      // f32[4096][512]    = 8388608
#define WS_NEED (WS_PQ + 8388608u)

// ---------- kernel 0: span meta + weight repack (merged) ----------
__global__ void k0_pack(const float* __restrict__ Wenc, const float* __restrict__ Ws1,
                        const float* __restrict__ Wc1, const float* __restrict__ Ws2,
                        const float* __restrict__ Wc2, const float* __restrict__ bs1,
                        const float* __restrict__ bc1, const float* __restrict__ bs2,
                        const float* __restrict__ bc2, __bf16* __restrict__ WencP,
                        __bf16* __restrict__ WT, __bf16* __restrict__ GT,
                        float* __restrict__ bsc, float* __restrict__ gbv,
                        int* __restrict__ starts, int* __restrict__ ends) {
  int idx = blockIdx.x * 256 + threadIdx.x;
  if (idx < 131072) {  // WencP[kc][n(512)][j]
    int j = idx & 7, n = (idx >> 3) & 511, kc = idx >> 12;
    int k = kc * 8 + j;
    float v = (n < 256) ? Wenc[k * 256 + n] : Wenc[(256 + k) * 256 + (n - 256)];
    WencP[idx] = (__bf16)v;
  }
  int i2 = idx - 131072;  // WT[kc][c(256)][j]
  if (i2 >= 0 && i2 < 65536) {
    int j = i2 & 7, c = (i2 >> 3) & 255, kc = i2 >> 11;
    int k = kc * 8 + j;
    float v = (c < 128) ? Ws1[k * 128 + c] : Wc1[k * 128 + (c - 128)];
    WT[i2] = (__bf16)v;
  }
  int i3 = idx - (131072 + 65536);  // GT[kc][c(16)][j]
  if (i3 >= 0 && i3 < 4096) {
    int j = i3 & 7, c = (i3 >> 3) & 15, kc = i3 >> 7;
    int k = kc * 8 + j;
    float v = 0.f;
    if (c == 0) { if (k < 128) v = Ws2[k]; }
    else { if (k >= 128) v = Wc2[(k - 128) * 15 + (c - 1)]; }
    GT[i3] = (__bf16)v;
  }
  int i4 = idx - (131072 + 65536 + 4096);
  if (i4 >= 0 && i4 < 256) bsc[i4] = (i4 < 128) ? bs1[i4] : bc1[i4 - 128];
  if (i4 >= 256 && i4 < 272) { int c = i4 - 256; gbv[c] = (c == 0) ? bs2[0] : bc2[c - 1]; }
  int mi = idx - (131072 + 65536 + 4096 + 272);  // span meta
  if (mi >= 0 && mi < 65536) {
    int i = mi >> 7, j = mi & 127;
    int len = min(100, S_ - i);
    if (j < len) {
      int cum;
      if (i <= 413) cum = 100 * i;
      else { int a = i - 413; cum = 41300 + 99 * a - (a * (a - 1)) / 2; }
      starts[cum + j] = i;
      ends[cum + j] = i + j;
    }
  }
}

// ---------- kernel 1: PQ = E @ [Wenc_P | Wenc_Q]  (M=4096,N=512,K=256), f32 out ----------
__global__ __launch_bounds__(256) void k1_pq(const float* __restrict__ E,
                                             const __bf16* __restrict__ WencP,
                                             const float* __restrict__ benc,
                                             float* __restrict__ PQ) {
  const int tid = threadIdx.x;
  const int w = tid >> 6, lane = tid & 63, llo = lane & 15, lhi = lane >> 4;
  const int mbase = blockIdx.x * 64 + w * 16;
  const int nbase = blockIdx.y * 64;
  const float* aptr = E + (size_t)(mbase + llo) * 256 + lhi * 8;
  float4_ acc[4];
#pragma unroll
  for (int tn = 0; tn < 4; tn++) acc[tn] = (float4_){0.f, 0.f, 0.f, 0.f};
#pragma unroll
  for (int ks = 0; ks < 8; ++ks) {
    float4_ e0 = *(const float4_*)(aptr + ks * 32);
    float4_ e1 = *(const float4_*)(aptr + ks * 32 + 4);
    bf16x8 af;
#pragma unroll
    for (int j = 0; j < 4; j++) { af[j] = (__bf16)e0[j]; af[4 + j] = (__bf16)e1[j]; }
#pragma unroll
    for (int tn = 0; tn < 4; tn++) {
      bf16x8 bfr = *(const bf16x8*)(WencP + ((ks * 4 + lhi) * 512 + nbase + tn * 16 + llo) * 8);
      acc[tn] = MFMA16(af, bfr, acc[tn]);
    }
  }
  // direct f32 stores (lane-consecutive cols -> coalesced 64B segments)
#pragma unroll
  for (int tn = 0; tn < 4; tn++) {
    int col = nbase + tn * 16 + llo;
    float bb = (col < 256) ? benc[col] : 0.f;  // fold b_enc into P half
#pragma unroll
    for (int r = 0; r < 4; r++) {
      int row = mbase + lhi * 4 + r;
      PQ[(size_t)row * 512 + col] = acc[tn][r] + bb;
    }
  }
}

// ---------- kernel 2: fused span head — 8 waves, one batch/block, k-major LDS ----------
// LDS: h[kc2=k/8][span ^ (kc2&7)][8 bf16]   (32 pages x 1KB; sc reuses identically)
__global__ __launch_bounds__(512, 4) void k2_main(
    const float* __restrict__ PQ, const int* __restrict__ starts, const int* __restrict__ ends,
    const float* __restrict__ wtab, const __bf16* __restrict__ WT, const __bf16* __restrict__ GT,
    const float* __restrict__ bsc, const float* __restrict__ gbv,
    float* __restrict__ outS, float* __restrict__ outL) {
  __shared__ __align__(16) unsigned char h_lds[32768];
  const int tile = blockIdx.x, b = blockIdx.y;
  const int tid = threadIdx.x;
  const int w = tid >> 6, lane = tid & 63, llo = lane & 15, lhi = lane >> 4;

  // ---- stage 1: h = relu(P[s]+Q[e]) + width[e-s] -> k-major LDS (all-f32 math) ----
  {
    const int rowbase = tid >> 5;  // 0..15 (span = i*16 + rowbase)
    const int ch = tid & 31;       // kc2 page = ch; k-cols = ch*8..+8
    const float* PQb = PQ + (size_t)b * (S_ * 512);
    const int c8 = ch * 8;
    unsigned char* wp = h_lds + (unsigned)ch * 1024u + (unsigned)((rowbase ^ (ch & 7)) << 4);
#pragma unroll
    for (int i = 0; i < 4; i++) {
      int span = min(tile * 64 + i * 16 + rowbase, NSPANS - 1);  // tail: real span, masked at store
      int s = starts[span], e = ends[span];
      float4_ p0 = *(const float4_*)(PQb + s * 512 + c8);
      float4_ p1 = *(const float4_*)(PQb + s * 512 + c8 + 4);
      float4_ q0 = *(const float4_*)(PQb + e * 512 + 256 + c8);
      float4_ q1 = *(const float4_*)(PQb + e * 512 + 256 + c8 + 4);
      float4_ w0 = *(const float4_*)(wtab + (e - s) * 256 + c8);
      float4_ w1 = *(const float4_*)(wtab + (e - s) * 256 + c8 + 4);
      bf16x8 hv;
#pragma unroll
      for (int j = 0; j < 4; j++) {
        hv[j] = (__bf16)(fmaxf(p0[j] + q0[j], 0.f) + w0[j]);
        hv[4 + j] = (__bf16)(fmaxf(p1[j] + q1[j], 0.f) + w1[j]);
      }
      *(bf16x8*)(wp + i * 256) = hv;
    }
  }
  __syncthreads();  // B1: h visible

  // ---- stage 2: D1^T[scCol][span] = sum_k Wsc[k][scCol]*h[span][k]; wave w: cols [32w,32w+32)
  // lane reads h[span = tn*16+llo][k = ks*32 + lhi*8 + 0..7] -> page ks*4+lhi
  // addr = ks*4096 + lhi*1024 + tn*256 + ((llo^lhi) ^ 4*(ks&1))*16 -> 2 bases + imm
  const unsigned char* hbE = h_lds + (unsigned)(lhi * 1024 + ((llo ^ lhi) << 4));
  const unsigned char* hbO = h_lds + (unsigned)(lhi * 1024 + (((llo ^ lhi) ^ 4) << 4));
  float4_ acc[2][4];
#pragma unroll
  for (int tm = 0; tm < 2; tm++)
#pragma unroll
    for (int tn = 0; tn < 4; tn++) acc[tm][tn] = (float4_){0.f, 0.f, 0.f, 0.f};
#pragma unroll
  for (int ks = 0; ks < 8; ++ks) {
    const unsigned char* hp = (ks & 1) ? hbO : hbE;  // static after unroll
    bf16x8 af[2], bfr[4];
#pragma unroll
    for (int tm = 0; tm < 2; tm++)
      af[tm] = *(const bf16x8*)(WT + ((ks * 4 + lhi) * 256 + w * 32 + tm * 16 + llo) * 8);
#pragma unroll
    for (int tn = 0; tn < 4; tn++)
      bfr[tn] = *(const bf16x8*)(hp + tn * 256 + ks * 4096);
#pragma unroll
    for (int tm = 0; tm < 2; tm++)
#pragma unroll
      for (int tn = 0; tn < 4; tn++) acc[tm][tn] = MFMA16(af[tm], bfr[tn], acc[tm][tn]);
  }
  __syncthreads();  // B2: all h reads done before overwriting LDS with sc

  // epilogue: sc = relu(acc + bsc) -> k-major LDS (reuse h_lds)
  // page kc2s = w*4+tm*2+(lhi>>1); addr = kc2s*1024 + ((span^(kc2s&7))<<4) + (lhi&1)*8
#pragma unroll
  for (int tm = 0; tm < 2; tm++) {
    const int kc2s = w * 4 + tm * 2 + (lhi >> 1);
    float4_ bq = *(const float4_*)(bsc + w * 32 + tm * 16 + lhi * 4);
    unsigned char* ep =
        h_lds + (unsigned)kc2s * 1024u + (unsigned)((llo ^ (kc2s & 7)) << 4) + (unsigned)((lhi & 1) << 3);
#pragma unroll
    for (int tn = 0; tn < 4; tn++) {
      bf16x4 x;
#pragma unroll
      for (int r = 0; r < 4; r++) x[r] = (__bf16)fmaxf(acc[tm][tn][r] + bq[r], 0.f);
      *(bf16x4*)(ep + tn * 256) = x;
    }
  }
  __syncthreads();  // B3: sc visible

  // ---- stage 3: D2^T[gcol][span] = sum_k G[k][gcol]*sc[span][k]; waves 0-3, 16 rows each
  if (w < 4) {
    const unsigned char* sbE = h_lds + (unsigned)(lhi * 1024 + w * 256 + ((llo ^ lhi) << 4));
    const unsigned char* sbO = h_lds + (unsigned)(lhi * 1024 + w * 256 + (((llo ^ lhi) ^ 4) << 4));
    float4_ a2 = (float4_){0.f, 0.f, 0.f, 0.f};
#pragma unroll
    for (int ks = 0; ks < 8; ++ks) {
      const unsigned char* sp = (ks & 1) ? sbO : sbE;
      bf16x8 ga = *(const bf16x8*)(GT + ((ks * 4 + lhi) * 16 + llo) * 8);
      bf16x8 sb = *(const bf16x8*)(sp + ks * 4096);
      a2 = MFMA16(ga, sb, a2);
    }
    const int span2 = tile * 64 + w * 16 + llo;
    if (span2 < NSPANS) {
      const float4_ gq = *(const float4_*)(gbv + lhi * 4);
      size_t base = (size_t)b * NSPANS + span2;
#pragma unroll
      for (int r = 0; r < 4; r++) {
        float v = a2[r] + gq[r];
        int gcol = lhi * 4 + r;
        if (gcol == 0) outS[base] = v;           // span_scores (B,N)
        else outL[base * 15 + (gcol - 1)] = v;   // type_logits (B,N,15)
      }
    }
  }
}

extern "C" void kernel_launch(void* const* d_in, const int* in_sizes, int n_in,
                              void* d_out, int out_size, void* d_ws, size_t ws_size,
                              hipStream_t stream) {
  if (ws_size < (size_t)WS_NEED) return;  // need ~9.2 MB scratch
  const float* E = (const float*)d_in[0];
  const float* Wenc = (const float*)d_in[1];
  const float* benc = (const float*)d_in[2];
  const float* wtab = (const float*)d_in[3];
  const float* Ws1 = (const float*)d_in[4];
  const float* bs1 = (const float*)d_in[5];
  const float* Ws2 = (const float*)d_in[6];
  const float* bs2 = (const float*)d_in[7];
  const float* Wc1 = (const float*)d_in[8];
  const float* bc1 = (const float*)d_in[9];
  const float* Wc2 = (const float*)d_in[10];
  const float* bc2 = (const float*)d_in[11];

  unsigned char* ws = (unsigned char*)d_ws;
  int* starts = (int*)(ws + WS_STARTS);
  int* ends = (int*)(ws + WS_ENDS);
  __bf16* WencP = (__bf16*)(ws + WS_WENCP);
  __bf16* WT = (__bf16*)(ws + WS_WT);
  __bf16* GT = (__bf16*)(ws + WS_GT);
  float* bsc = (float*)(ws + WS_BSC);
  float* gbv = (float*)(ws + WS_GB);
  float* PQ = (float*)(ws + WS_PQ);

  float* outS = (float*)d_out;
  float* outL = outS + (size_t)B_ * NSPANS;

  k0_pack<<<dim3(1042), dim3(256), 0, stream>>>(Wenc, Ws1, Wc1, Ws2, Wc2, bs1, bc1, bs2, bc2,
                                                WencP, WT, GT, bsc, gbv, starts, ends);
  k1_pq<<<dim3(64, 8), dim3(256), 0, stream>>>(E, WencP, benc, PQ);
  k2_main<<<dim3(NTILES, B_), dim3(512), 0, stream>>>(PQ, starts, ends, wtab, WT, GT, bsc, gbv,
                                                      outS, outL);
}